// Round 4
// baseline (238.430 us; speedup 1.0000x reference)
//
#include <hip/hip_runtime.h>
#include <stdint.h>

#define B_     64
#define N_     197
#define DIM_   768
#define HEADS_ 12
#define HD_    64
#define M_     (B_*N_)      // 12608
#define K3_    (3*DIM_)     // 2304
#define NP_    208          // padded N (13*16)
#define KSTR_  72           // attn K_lds row stride (f16)
#define VSTR_  232          // attn VT / P row stride (f16)
#define SCALE_ 0.125f
#define GK_    768          // GEMM K (both gemms)
#define NKT_   12           // GK_/64
#define NIT_   6            // NKT_/2

typedef _Float16 f16x8 __attribute__((ext_vector_type(8)));
typedef _Float16 f16x4 __attribute__((ext_vector_type(4)));
typedef _Float16 f16x2 __attribute__((ext_vector_type(2)));
typedef float    f32x4 __attribute__((ext_vector_type(4)));

__device__ __forceinline__ void gload_lds16(const void* g, void* l) {
    __builtin_amdgcn_global_load_lds(
        (const __attribute__((address_space(1))) uint32_t*)g,
        (__attribute__((address_space(3))) uint32_t*)l, 16, 0, 0);
}

// ---------------- f32 -> f16 convert ----------------
__global__ __launch_bounds__(256) void cvt_f32_f16(const float* __restrict__ s,
                                                   _Float16* __restrict__ d, int n4) {
    int i = blockIdx.x * 256 + threadIdx.x;
    if (i < n4) {
        const float4 v = *(const float4*)(s + (size_t)i * 4);
        f16x4 o;
        o[0] = (_Float16)v.x; o[1] = (_Float16)v.y;
        o[2] = (_Float16)v.z; o[3] = (_Float16)v.w;
        *(f16x4*)(d + (size_t)i * 4) = o;
    }
}

// ---------------- transposed rel-pos bias: biasT[h][k][q], padded 208x208 ----------------
__global__ __launch_bounds__(256) void biasT_pre(const int* __restrict__ rel_index,
                                                 const float* __restrict__ rel_table,
                                                 float* __restrict__ biasT) {
    int t = blockIdx.x * 256 + threadIdx.x;
    if (t < HEADS_ * NP_ * NP_) {
        int h = t / (NP_ * NP_), rem = t - h * (NP_ * NP_);
        int k = rem / NP_, q = rem - k * NP_;
        float v;
        if (k >= N_)      v = -1e30f;   // padded key -> exp()->0
        else if (q >= N_) v = 0.f;      // padded query -> finite, never stored
        else              v = rel_table[rel_index[q * N_ + k] * HEADS_ + h];
        biasT[t] = v;
    }
}

// ---------------- 8-phase 256x256 MFMA GEMM: C[M x Nout] = A[M x 768] * Bw[Nout x 768]^T ----
// LDS: 4 slots per operand: slot = buf*2 + ksh, each [256 rows][32 k] f16 (16KB), swizzled.
// Swizzle: granule (16B) involution gg ^= (gg>>3)&7 within each 1024-granule half-tile.
#define VMW(N) asm volatile("s_waitcnt vmcnt(" #N ")" ::: "memory")

#define MFMA16(MH) \
    acc[(MH)*4+0][0] = __builtin_amdgcn_mfma_f32_16x16x32_f16(a0, b0, acc[(MH)*4+0][0], 0,0,0); \
    acc[(MH)*4+0][1] = __builtin_amdgcn_mfma_f32_16x16x32_f16(a0, b1, acc[(MH)*4+0][1], 0,0,0); \
    acc[(MH)*4+0][2] = __builtin_amdgcn_mfma_f32_16x16x32_f16(a0, b2, acc[(MH)*4+0][2], 0,0,0); \
    acc[(MH)*4+0][3] = __builtin_amdgcn_mfma_f32_16x16x32_f16(a0, b3, acc[(MH)*4+0][3], 0,0,0); \
    acc[(MH)*4+1][0] = __builtin_amdgcn_mfma_f32_16x16x32_f16(a1, b0, acc[(MH)*4+1][0], 0,0,0); \
    acc[(MH)*4+1][1] = __builtin_amdgcn_mfma_f32_16x16x32_f16(a1, b1, acc[(MH)*4+1][1], 0,0,0); \
    acc[(MH)*4+1][2] = __builtin_amdgcn_mfma_f32_16x16x32_f16(a1, b2, acc[(MH)*4+1][2], 0,0,0); \
    acc[(MH)*4+1][3] = __builtin_amdgcn_mfma_f32_16x16x32_f16(a1, b3, acc[(MH)*4+1][3], 0,0,0); \
    acc[(MH)*4+2][0] = __builtin_amdgcn_mfma_f32_16x16x32_f16(a2, b0, acc[(MH)*4+2][0], 0,0,0); \
    acc[(MH)*4+2][1] = __builtin_amdgcn_mfma_f32_16x16x32_f16(a2, b1, acc[(MH)*4+2][1], 0,0,0); \
    acc[(MH)*4+2][2] = __builtin_amdgcn_mfma_f32_16x16x32_f16(a2, b2, acc[(MH)*4+2][2], 0,0,0); \
    acc[(MH)*4+2][3] = __builtin_amdgcn_mfma_f32_16x16x32_f16(a2, b3, acc[(MH)*4+2][3], 0,0,0); \
    acc[(MH)*4+3][0] = __builtin_amdgcn_mfma_f32_16x16x32_f16(a3, b0, acc[(MH)*4+3][0], 0,0,0); \
    acc[(MH)*4+3][1] = __builtin_amdgcn_mfma_f32_16x16x32_f16(a3, b1, acc[(MH)*4+3][1], 0,0,0); \
    acc[(MH)*4+3][2] = __builtin_amdgcn_mfma_f32_16x16x32_f16(a3, b2, acc[(MH)*4+3][2], 0,0,0); \
    acc[(MH)*4+3][3] = __builtin_amdgcn_mfma_f32_16x16x32_f16(a3, b3, acc[(MH)*4+3][3], 0,0,0)

#define PHASE(PK, MH, RDB, STG, WT) do { \
    const _Float16* Ab_ = &As[PK][wm * 4096 + gl8]; \
    a0 = *(const f16x8*)(Ab_ +  0 + (MH)*2048); \
    a1 = *(const f16x8*)(Ab_ + 512 + (MH)*2048); \
    a2 = *(const f16x8*)(Ab_ + 1024 + (MH)*2048); \
    a3 = *(const f16x8*)(Ab_ + 1536 + (MH)*2048); \
    if (RDB) { \
        const _Float16* Bb_ = &Bs[PK][wn * 2048 + gl8]; \
        b0 = *(const f16x8*)(Bb_);        b1 = *(const f16x8*)(Bb_ + 512); \
        b2 = *(const f16x8*)(Bb_ + 1024); b3 = *(const f16x8*)(Bb_ + 1536); \
    } \
    STG; \
    WT; \
    __builtin_amdgcn_s_barrier(); \
    asm volatile("s_waitcnt lgkmcnt(0)" ::: "memory"); \
    __builtin_amdgcn_sched_barrier(0); \
    __builtin_amdgcn_s_setprio(1); \
    MFMA16(MH); \
    __builtin_amdgcn_s_setprio(0); \
    __builtin_amdgcn_s_barrier(); \
} while (0)

__global__ __launch_bounds__(512, 2) void gemm8(
    const _Float16* __restrict__ A, const _Float16* __restrict__ Bw,
    int M, int Nout, int mode,
    const float* __restrict__ qb, const float* __restrict__ vb,
    const float* __restrict__ pb, const int* __restrict__ b_idx,
    _Float16* __restrict__ out_h, float* __restrict__ out_f)
{
    __shared__ __align__(16) _Float16 As[4][8192];
    __shared__ __align__(16) _Float16 Bs[4][8192];

    const int tid  = threadIdx.x;
    const int lane = tid & 63, w = tid >> 6;
    const int wm = w >> 2, wn = w & 3;              // 2 M-waves x 4 N-waves
    const int fr = lane & 15, g = lane >> 4;
    const int gl8 = ((4 * fr + g) ^ (fr >> 1)) * 8; // swizzled read granule*8 elems
    const int lx = lane ^ (lane >> 3);              // inverse-swizzle for staging source
    const int sr = lx >> 2, sc8 = (lx & 3) * 8;
    const int m0 = blockIdx.y * 256, n0 = blockIdx.x * 256;

    f32x4 acc[8][4];
    #pragma unroll
    for (int i = 0; i < 8; ++i)
        #pragma unroll
        for (int j = 0; j < 4; ++j) acc[i][j] = (f32x4)0.f;

    f16x8 a0{}, a1{}, a2{}, a3{}, b0{}, b1{}, b2{}, b3{};

    // stage one 16KB half-tile (slot pk): 2 gload_lds issues per thread
    auto stA = [&](int pk, int kt) {
        #pragma unroll
        for (int iss = 0; iss < 2; ++iss) {
            int r = w * 32 + iss * 16 + sr;
            int grow = m0 + r; if (grow >= M) grow = M - 1;
            gload_lds16(A + (size_t)grow * GK_ + kt * 64 + (pk & 1) * 32 + sc8,
                        &As[pk][w * 1024 + iss * 512]);
        }
    };
    auto stB = [&](int pk, int kt) {
        #pragma unroll
        for (int iss = 0; iss < 2; ++iss) {
            int r = n0 + w * 32 + iss * 16 + sr;
            gload_lds16(Bw + (size_t)r * GK_ + kt * 64 + (pk & 1) * 32 + sc8,
                        &Bs[pk][w * 1024 + iss * 512]);
        }
    };

    // ---- prologue: buf0 (kt 0, both k-halves) + buf1.ks0 (kt 1) ----
    stA(0, 0); stB(0, 0); stA(1, 0); stB(1, 0); stA(2, 1); stB(2, 1);
    VMW(4);                       // oldest 8 of 12 done => buf0 fully landed
    __builtin_amdgcn_s_barrier();

    // ---- main loop: iter t computes kt 2t (slots 0,1) and 2t+1 (slots 2,3) ----
    for (int t = 0; t < NIT_; ++t) {
        const int k1 = 2 * t + 1, k2 = 2 * t + 2, k3 = 2 * t + 3;
        const bool last = (t == NIT_ - 1);
        PHASE(0, 0, 1, stA(3, k1), );
        PHASE(0, 1, 0, stB(3, k1), );
        PHASE(1, 0, 1, if (!last) stA(0, k2), );
        PHASE(1, 1, 0, if (!last) stB(0, k2), if (last) { VMW(0); } else { VMW(4); });
        PHASE(2, 0, 1, if (!last) stA(1, k2), );
        PHASE(2, 1, 0, if (!last) stB(1, k2), );
        PHASE(3, 0, 1, if (!last) stA(2, k3), );
        PHASE(3, 1, 0, if (!last) stB(2, k3), if (!last) { VMW(4); });
    }

    // ---- epilogue: C/D layout col=fr, row=g*4+rr ----
    #pragma unroll
    for (int mi = 0; mi < 8; ++mi) {
        #pragma unroll
        for (int rr = 0; rr < 4; ++rr) {
            const int row = m0 + wm * 128 + mi * 16 + g * 4 + rr;
            if (row < M) {
                const int bi = b_idx[row / N_];
                #pragma unroll
                for (int ni = 0; ni < 4; ++ni) {
                    const int col = n0 + wn * 64 + ni * 16 + fr;
                    float v = acc[mi][ni][rr];
                    if (mode == 0) {
                        float bias = 0.f;
                        if (col < DIM_) bias = qb[bi * DIM_ + col];
                        else if (col >= 2 * DIM_) bias = vb[bi * DIM_ + (col - 2 * DIM_)];
                        out_h[(size_t)row * Nout + col] = (_Float16)(v + bias);
                    } else {
                        out_f[(size_t)row * Nout + col] = v + pb[bi * DIM_ + col];
                    }
                }
            }
        }
    }
}

// ---------------- MFMA attention: one block per (b, h, 64-row q-tile) ----------------
__global__ __launch_bounds__(256) void attn_mfma(
    const _Float16* __restrict__ qkv, const float* __restrict__ biasT,
    _Float16* __restrict__ ctx)
{
    __shared__ __align__(16) _Float16 KP[NP_ * KSTR_];   // K tile, reused as P tile
    __shared__ __align__(16) _Float16 VT[HD_ * VSTR_];   // V^T tile

    const int b = blockIdx.z, h = blockIdx.y, rt = blockIdx.x;
    const int r0 = rt * 64;
    const int tid = threadIdx.x, lane = tid & 63, w = tid >> 6;
    const int fr = lane & 15, g = lane >> 4;

    const size_t baseQ = (size_t)b * N_ * K3_ + h * HD_;
    const size_t baseK = baseQ + DIM_;
    const size_t baseV = baseQ + 2 * DIM_;

    for (int idx = tid; idx < NP_ * 8; idx += 256) {
        int row = idx % NP_, dc = idx / NP_;
        int gk = min(row, N_ - 1);
        f16x8 v = *(const f16x8*)(qkv + baseK + (size_t)gk * K3_ + dc * 8);
        *(f16x8*)(KP + row * KSTR_ + dc * 8) = v;
    }
    for (int idx = tid; idx < 112 * 8; idx += 256) {
        int jp = idx % 112, dc = idx / 112;
        int j0 = 2 * jp, j1 = 2 * jp + 1;
        f16x8 zz = {};
        f16x8 v0 = (j0 < N_) ? *(const f16x8*)(qkv + baseV + (size_t)j0 * K3_ + dc * 8) : zz;
        f16x8 v1 = (j1 < N_) ? *(const f16x8*)(qkv + baseV + (size_t)j1 * K3_ + dc * 8) : zz;
        #pragma unroll
        for (int e = 0; e < 8; ++e) {
            f16x2 p; p[0] = v0[e]; p[1] = v1[e];
            *(f16x2*)(VT + (dc * 8 + e) * VSTR_ + 2 * jp) = p;
        }
    }
    const int qrow = min(r0 + w * 16 + fr, N_ - 1);
    f16x8 qf[2];
    qf[0] = *(const f16x8*)(qkv + baseQ + (size_t)qrow * K3_ + g * 8);
    qf[1] = *(const f16x8*)(qkv + baseQ + (size_t)qrow * K3_ + 32 + g * 8);

    __syncthreads();

    f32x4 acc[13];
    #pragma unroll
    for (int jf = 0; jf < 13; ++jf) acc[jf] = (f32x4)0.f;
    #pragma unroll
    for (int jf = 0; jf < 13; ++jf) {
        #pragma unroll
        for (int kk = 0; kk < 2; ++kk) {
            f16x8 a = *(const f16x8*)&KP[(jf * 16 + fr) * KSTR_ + kk * 32 + g * 8];
            acc[jf] = __builtin_amdgcn_mfma_f32_16x16x32_f16(a, qf[kk], acc[jf], 0, 0, 0);
        }
    }

    const int qb_ = min(r0 + w * 16 + fr, NP_ - 1);
    const float* bp = biasT + (size_t)h * NP_ * NP_ + qb_;
    float mx = -3e38f;
    #pragma unroll
    for (int jf = 0; jf < 13; ++jf) {
        #pragma unroll
        for (int r = 0; r < 4; ++r) {
            int k = jf * 16 + g * 4 + r;
            float s = acc[jf][r] * SCALE_ + bp[(size_t)k * NP_];
            acc[jf][r] = s;
            mx = fmaxf(mx, s);
        }
    }
    mx = fmaxf(mx, __shfl_xor(mx, 16));
    mx = fmaxf(mx, __shfl_xor(mx, 32));
    float sum = 0.f;
    #pragma unroll
    for (int jf = 0; jf < 13; ++jf) {
        #pragma unroll
        for (int r = 0; r < 4; ++r) {
            float e = __expf(acc[jf][r] - mx);
            acc[jf][r] = e;
            sum += e;
        }
    }
    sum += __shfl_xor(sum, 16);
    sum += __shfl_xor(sum, 32);
    const float inv = 1.f / sum;

    __syncthreads();

    #pragma unroll
    for (int jf = 0; jf < 13; ++jf) {
        f16x4 p;
        #pragma unroll
        for (int r = 0; r < 4; ++r) p[r] = (_Float16)(acc[jf][r] * inv);
        *(f16x4*)(KP + (size_t)(w * 16 + fr) * VSTR_ + jf * 16 + g * 4) = p;
    }
    {
        f16x4 z = {};
        *(f16x4*)(KP + (size_t)(w * 16 + fr) * VSTR_ + NP_ + g * 4) = z;
    }
    __syncthreads();

    f32x4 oacc[4];
    #pragma unroll
    for (int dj = 0; dj < 4; ++dj) oacc[dj] = (f32x4)0.f;
    #pragma unroll
    for (int ks = 0; ks < 7; ++ks) {
        f16x8 a = *(const f16x8*)&KP[(size_t)(w * 16 + fr) * VSTR_ + ks * 32 + g * 8];
        #pragma unroll
        for (int dj = 0; dj < 4; ++dj) {
            f16x8 bf = *(const f16x8*)&VT[(dj * 16 + fr) * VSTR_ + ks * 32 + g * 8];
            oacc[dj] = __builtin_amdgcn_mfma_f32_16x16x32_f16(a, bf, oacc[dj], 0, 0, 0);
        }
    }
    #pragma unroll
    for (int dj = 0; dj < 4; ++dj) {
        #pragma unroll
        for (int r = 0; r < 4; ++r) {
            const int q = r0 + w * 16 + g * 4 + r;
            if (q < N_)
                ctx[((size_t)b * N_ + q) * DIM_ + h * HD_ + dj * 16 + fr] =
                    (_Float16)oacc[dj][r];
        }
    }
}

// ---------------- launcher ----------------
extern "C" void kernel_launch(void* const* d_in, const int* in_sizes, int n_in,
                              void* d_out, int out_size, void* d_ws, size_t ws_size,
                              hipStream_t stream) {
    const float* x     = (const float*)d_in[0];
    const float* wqkv  = (const float*)d_in[1];
    const float* qb    = (const float*)d_in[2];
    const float* vb    = (const float*)d_in[3];
    const float* rt    = (const float*)d_in[4];
    const float* wproj = (const float*)d_in[5];
    const float* pbias = (const float*)d_in[6];
    const int* b_idx   = (const int*)d_in[7];
    const int* rel_idx = (const int*)d_in[8];
    float* out = (float*)d_out;

    char* ws = (char*)d_ws;
    size_t off = 0;
    auto alloc = [&](size_t bytes) -> void* {
        void* p = ws + off; off += (bytes + 255) & ~(size_t)255; return p;
    };
    _Float16* xb    = (_Float16*)alloc((size_t)M_ * DIM_ * 2);
    _Float16* wqh   = (_Float16*)alloc((size_t)K3_ * DIM_ * 2);
    _Float16* wph   = (_Float16*)alloc((size_t)DIM_ * DIM_ * 2);
    _Float16* qkvh  = (_Float16*)alloc((size_t)M_ * K3_ * 2);
    _Float16* ctx   = (_Float16*)alloc((size_t)M_ * DIM_ * 2);
    float*    biasT = (float*)alloc((size_t)HEADS_ * NP_ * NP_ * 4);

    cvt_f32_f16<<<dim3((M_ * DIM_ / 4 + 255) / 256), 256, 0, stream>>>(x, xb, M_ * DIM_ / 4);
    cvt_f32_f16<<<dim3((K3_ * DIM_ / 4 + 255) / 256), 256, 0, stream>>>(wqkv, wqh, K3_ * DIM_ / 4);
    cvt_f32_f16<<<dim3((DIM_ * DIM_ / 4 + 255) / 256), 256, 0, stream>>>(wproj, wph, DIM_ * DIM_ / 4);
    biasT_pre<<<dim3((HEADS_ * NP_ * NP_ + 255) / 256), 256, 0, stream>>>(rel_idx, rt, biasT);

    gemm8<<<dim3(K3_ / 256, (M_ + 255) / 256), 512, 0, stream>>>(
        xb, wqh, M_, K3_, 0, qb, vb, nullptr, b_idx, qkvh, nullptr);

    attn_mfma<<<dim3(4, HEADS_, B_), 256, 0, stream>>>(qkvh, biasT, ctx);

    gemm8<<<dim3(DIM_ / 256, (M_ + 255) / 256), 512, 0, stream>>>(
        ctx, wph, M_, DIM_, 1, nullptr, nullptr, pbias, b_idx, nullptr, out);
}